// Round 7
// baseline (383.880 us; speedup 1.0000x reference)
//
#include <hip/hip_runtime.h>
#include <stdint.h>

#define BB 4
#define LL 16384
#define CC 512
#define MM (BB * LL)  // 65536

typedef unsigned short u16;
typedef __bf16 bf16x8 __attribute__((ext_vector_type(8)));
typedef float f32x4 __attribute__((ext_vector_type(4)));
typedef u16 u16x8 __attribute__((ext_vector_type(8)));
typedef u16 u16x4 __attribute__((ext_vector_type(4)));

__device__ __forceinline__ u16 f2bf(float f) {
  return __builtin_bit_cast(u16, (__bf16)f);
}

__device__ __forceinline__ void gl_lds16(const void* g, void* l) {
  __builtin_amdgcn_global_load_lds((const __attribute__((address_space(1))) void*)g,
                                   (__attribute__((address_space(3))) void*)l,
                                   16, 0, 0);
}

// ------------- fused weight transpose+convert: W[K][N] -> Wt[N][K] bf16 -------------
__global__ void tcvt3_kernel(const float* __restrict__ Wq, const float* __restrict__ Wkv,
                             const float* __restrict__ Wfc, u16* __restrict__ Wq_t,
                             u16* __restrict__ Wkv_t, u16* __restrict__ Wfc_t) {
  int idx = blockIdx.x * blockDim.x + threadIdx.x;  // 0 .. 1048575
  const float* W; u16* Wt; int N, li;
  if (idx < 262144)      { W = Wq;  Wt = Wq_t;  N = 512;  li = idx; }
  else if (idx < 786432) { W = Wkv; Wt = Wkv_t; N = 1024; li = idx - 262144; }
  else                   { W = Wfc; Wt = Wfc_t; N = 512;  li = idx - 786432; }
  int n = li / 512, k = li % 512;
  Wt[li] = f2bf(W[k * N + n]);
}

// ---------------- 256x256 8-phase NT GEMM: C[M][N] = A[M][K] * Bt[N][K]^T ----------
// BM=BN=256, BK=64, 8 waves (2M x 4N), double-buffered LDS, T2 XOR-swizzle,
// counted vmcnt, setprio around MFMA clusters. K must be a multiple of 128.
//
// A_F32=false: A staged via global_load_lds. Discipline: A(u+1) -> idle-parity
//   buffer @p1/p2; B(u+2) -> same-parity @p3/p4; end-of-tile vmcnt(4).
// A_F32=true: A is fp32 in global; staged via registers with fused convert
//   (T14 issue-early/write-late): p1 issues 8 dwordx4 fp32 loads of A(u+1);
//   p3 does vmcnt(0) (also drains B(u+1) gl_lds, issued 5 phases earlier),
//   converts, ds_write_b128 -> idle buffer; B(u+2) still @p3/p4; no
//   end-of-tile vmcnt (B(u+2) drained by next tile's p3 vmcnt(0)). A-writes
//   are covered by each wave's p3/p4 lgkmcnt(0) before the tile-end barrier;
//   first read of the written region is tile u+1 p1.
template <bool A_F32, bool OUT_F32>
__global__ __launch_bounds__(512, 2) void gemm256(const void* __restrict__ Ap,
                                                  const u16* __restrict__ Bt,
                                                  void* __restrict__ Cp,
                                                  int M, int N, int K) {
  __shared__ __align__(16) u16 Al[2][16384];
  __shared__ __align__(16) u16 Bl[2][16384];
  const int nbn = N >> 8;
  const int nwg = gridDim.x;
  const int bid0 = blockIdx.x;
  const int cpx = nwg >> 3;  // grid % 8 == 0 for all our shapes
  const int bid = (bid0 & 7) * cpx + (bid0 >> 3);
  const int bm = bid / nbn, bn = bid % nbn;
  const size_t row0 = (size_t)bm << 8, col0 = (size_t)bn << 8;
  const int tid = threadIdx.x, lane = tid & 63;
  const int wv = tid >> 6, wm = wv >> 2, wn = wv & 3;
  const int ro = lane & 15, g4 = lane >> 4;
  const int NT = K >> 6;

  const u16* A16 = (const u16*)Ap;
  const float* A32 = (const float*)Ap;

  // staging geometry: chunk ci covers (row=ci>>3, colgroup=ci&7) of the 256x64 tile.
  // LDS dest is LINEAR; global source colgroup pre-swizzled: gg = g ^ (row&7).
  const int cis[4] = {tid, tid + 512, tid + 1024, tid + 1536};
  int crs[4], cgs[4];
#pragma unroll
  for (int c = 0; c < 4; ++c) { crs[c] = cis[c] >> 3; cgs[c] = (cis[c] & 7) ^ (crs[c] & 7); }
  const int r0 = crs[0], g0 = cgs[0], r1 = crs[1], g1 = cgs[1];

  auto stageA16 = [&](int half, int kt, u16* L) {
    gl_lds16(A16 + (row0 + half * 128 + r0) * (size_t)K + kt * 64 + g0 * 8, L + half * 8192 + tid * 8);
    gl_lds16(A16 + (row0 + half * 128 + r1) * (size_t)K + kt * 64 + g1 * 8, L + half * 8192 + (tid + 512) * 8);
  };
  auto stageB = [&](int half, int kt, u16* L) {
    gl_lds16(Bt + (col0 + half * 128 + r0) * (size_t)K + kt * 64 + g0 * 8, L + half * 8192 + tid * 8);
    gl_lds16(Bt + (col0 + half * 128 + r1) * (size_t)K + kt * 64 + g1 * 8, L + half * 8192 + (tid + 512) * 8);
  };

  // fp32 A reg-staging: 4 chunks/thread, 2 dwordx4 each, fused cvt on write.
  f32x4 av[4][2];
  auto aload = [&](int kt) {
#pragma unroll
    for (int c = 0; c < 4; ++c) {
      const float* s = A32 + (row0 + crs[c]) * (size_t)K + kt * 64 + cgs[c] * 8;
      av[c][0] = *reinterpret_cast<const f32x4*>(s);
      av[c][1] = *reinterpret_cast<const f32x4*>(s + 4);
    }
  };
  auto awrite = [&](u16* L) {
#pragma unroll
    for (int c = 0; c < 4; ++c) {
      bf16x8 wq;
#pragma unroll
      for (int e = 0; e < 8; ++e) wq[e] = (__bf16)av[c][e >> 2][e & 3];
      *reinterpret_cast<bf16x8*>(L + cis[c] * 8) = wq;
    }
  };

  // ds_read offsets (u16 elements), swizzled: phys colgroup = logical ^ (row&7)
  const int aB = (wm * 128 + ro) * 64;
  const int bB = (wn * 64 + ro) * 64;
  const int sw0 = (g4 ^ (ro & 7)) * 8;
  const int sw1 = ((g4 + 4) ^ (ro & 7)) * 8;

  auto ldf = [&](const u16* p) { return *reinterpret_cast<const bf16x8*>(p); };

  f32x4 acc[8][4] = {};

  // prologue
  if (A_F32) {
    aload(0);
    stageB(0, 0, Bl[0]); stageB(1, 0, Bl[0]);
    stageB(0, 1, Bl[1]); stageB(1, 1, Bl[1]);
    asm volatile("s_waitcnt vmcnt(4)" ::: "memory");  // drain aload(0)+B(0); B(1) in flight
    awrite(Al[0]);
    asm volatile("s_waitcnt lgkmcnt(0)" ::: "memory");
  } else {
    stageA16(0, 0, Al[0]); stageA16(1, 0, Al[0]); stageB(0, 0, Bl[0]); stageB(1, 0, Bl[0]);
    stageB(0, 1, Bl[1]); stageB(1, 1, Bl[1]);
    asm volatile("s_waitcnt vmcnt(4)" ::: "memory");  // drain A(0)+B(0); B(1) in flight
  }
  __builtin_amdgcn_s_barrier();

  for (int t = 0; t < NT; t += 2) {
#pragma unroll
    for (int half = 0; half < 2; ++half) {
      const int u = t + half;
      u16* LA = Al[half];
      u16* LB = Bl[half];
      u16* LAn = Al[half ^ 1];
      const bool stA = (u + 1) < NT;
      const bool stB = (u + 2) < NT;
      bf16x8 bfr[4][2], af[2][2];

      // ---- phase 1: all B frags + A m0,m1; issue A(u+1) (regs or gl_lds) ----
      if (A_F32) { if (stA) aload(u + 1); }
#pragma unroll
      for (int n = 0; n < 4; ++n) {
        bfr[n][0] = ldf(LB + bB + n * 1024 + sw0);
        bfr[n][1] = ldf(LB + bB + n * 1024 + sw1);
      }
      af[0][0] = ldf(LA + aB + sw0);        af[0][1] = ldf(LA + aB + sw1);
      af[1][0] = ldf(LA + aB + 1024 + sw0); af[1][1] = ldf(LA + aB + 1024 + sw1);
      if (!A_F32) { if (stA) stageA16(0, u + 1, LAn); }
      __builtin_amdgcn_s_barrier();
      asm volatile("s_waitcnt lgkmcnt(0)" ::: "memory");
      __builtin_amdgcn_sched_barrier(0);
      __builtin_amdgcn_s_setprio(1);
#pragma unroll
      for (int m = 0; m < 2; ++m)
#pragma unroll
        for (int n = 0; n < 4; ++n) {
          acc[m][n] = __builtin_amdgcn_mfma_f32_16x16x32_bf16(af[m][0], bfr[n][0], acc[m][n], 0, 0, 0);
          acc[m][n] = __builtin_amdgcn_mfma_f32_16x16x32_bf16(af[m][1], bfr[n][1], acc[m][n], 0, 0, 0);
        }
      __builtin_amdgcn_s_setprio(0);
      __builtin_amdgcn_s_barrier();

      // ---- phases 2..4 ----
#pragma unroll
      for (int ph = 1; ph < 4; ++ph) {
        af[0][0] = ldf(LA + aB + (2 * ph) * 1024 + sw0);
        af[0][1] = ldf(LA + aB + (2 * ph) * 1024 + sw1);
        af[1][0] = ldf(LA + aB + (2 * ph + 1) * 1024 + sw0);
        af[1][1] = ldf(LA + aB + (2 * ph + 1) * 1024 + sw1);
        if (A_F32) {
          // p2: nothing. p3: drain A-loads (+B(u+1)), convert+write, stage B(u+2)h0.
          // p4: stage B(u+2)h1.
          if (ph == 2) {
            asm volatile("s_waitcnt vmcnt(0)" ::: "memory");
            if (stA) awrite(LAn);
            if (stB) stageB(0, u + 2, LB);
          } else if (ph == 3) {
            if (stB) stageB(1, u + 2, LB);
          }
        } else {
          if (ph == 1) { if (stA) stageA16(1, u + 1, LAn); }
          else if (ph == 2) { if (stB) stageB(0, u + 2, LB); }
          else { if (stB) stageB(1, u + 2, LB); }
        }
        __builtin_amdgcn_s_barrier();
        asm volatile("s_waitcnt lgkmcnt(0)" ::: "memory");
        __builtin_amdgcn_sched_barrier(0);
        __builtin_amdgcn_s_setprio(1);
#pragma unroll
        for (int m = 0; m < 2; ++m)
#pragma unroll
          for (int n = 0; n < 4; ++n) {
            acc[2 * ph + m][n] =
                __builtin_amdgcn_mfma_f32_16x16x32_bf16(af[m][0], bfr[n][0], acc[2 * ph + m][n], 0, 0, 0);
            acc[2 * ph + m][n] =
                __builtin_amdgcn_mfma_f32_16x16x32_bf16(af[m][1], bfr[n][1], acc[2 * ph + m][n], 0, 0, 0);
          }
        __builtin_amdgcn_s_setprio(0);
        if (!A_F32 && ph == 3) {
          if (stB) asm volatile("s_waitcnt vmcnt(4)" ::: "memory");
          else     asm volatile("s_waitcnt vmcnt(0)" ::: "memory");
        }
        __builtin_amdgcn_s_barrier();
      }
    }
  }

  // epilogue: C write
#pragma unroll
  for (int m = 0; m < 8; ++m)
#pragma unroll
    for (int n = 0; n < 4; ++n)
#pragma unroll
      for (int j = 0; j < 4; ++j) {
        size_t r = row0 + wm * 128 + m * 16 + g4 * 4 + j;
        size_t c = col0 + wn * 64 + n * 16 + ro;
        if (OUT_F32)
          reinterpret_cast<float*>(Cp)[r * N + c] = acc[m][n][j];
        else
          reinterpret_cast<u16*>(Cp)[r * N + c] = f2bf(acc[m][n][j]);
      }
}

// ---------------- window attention ----------------
// grid: b*512 + w*8 + h  (2048 blocks), 512 threads (8 waves, 32 q-rows each).
// K in LDS via global_load_lds with pre-swizzled source (32KB); V transposed in
// LDS, XOR-swizzled (32KB); P per-wave quarter-split, XOR-swizzled (16KB).
// Total exactly 80KB -> 2 blocks/CU.
__global__ __launch_bounds__(512, 4) void attn_kernel(const u16* __restrict__ qp,
                                                      const u16* __restrict__ kvp,
                                                      u16* __restrict__ o) {
  __shared__ __align__(16) u16 Kl[256 * 64];
  __shared__ __align__(16) u16 Vt[64 * 256];
  __shared__ __align__(16) u16 Pl[8 * 1024];
  const int bid = blockIdx.x;
  const int h = bid & 7, w = (bid >> 3) & 63, b = bid >> 9;
  const int w1 = w >> 3, w2 = w & 7;
  const int tid = threadIdx.x, lane = tid & 63, wv = tid >> 6;

  auto lrow = [&](int t) { return (w1 * 16 + (t >> 4)) * 128 + w2 * 16 + (t & 15); };

  // stage K: 2048 16B chunks; chunk ci = (row r = ci>>3, colgroup g = ci&7).
  // LDS dest linear; global source colgroup pre-swizzled g^(r&7).
#pragma unroll
  for (int p = 0; p < 4; ++p) {
    int ci = tid + p * 512;
    int r = ci >> 3, g = (ci & 7) ^ (r & 7);
    gl_lds16(kvp + ((size_t)(b * LL + lrow(r))) * 1024 + h * 64 + g * 8, Kl + ci * 8);
  }
  // stage V transposed, swizzled: logical (d, tk) at phys d*256 + ((tk>>3)^(d&7))*8 + (tk&7)
  {
    const int tk = tid >> 1, half = tid & 1;
    const size_t base = ((size_t)(b * LL + lrow(tk))) * 1024 + 512 + h * 64 + half * 32;
#pragma unroll
    for (int c = 0; c < 4; ++c) {
      u16x8 vx = *reinterpret_cast<const u16x8*>(kvp + base + c * 8);
#pragma unroll
      for (int e = 0; e < 8; ++e) {
        int d = half * 32 + c * 8 + e;
        Vt[d * 256 + (((tk >> 3) ^ (d & 7)) * 8) + (tk & 7)] = vx[e];
      }
    }
  }
  __syncthreads();

  const int ro = lane & 15;       // low nibble
  const int g4 = lane >> 4;       // lane group 0..3
  const float scale = 0.125f;     // hd^-0.5, hd=64
  const int swA = (g4 ^ (ro & 7)) * 8;
  const int swB = ((g4 + 4) ^ (ro & 7)) * 8;
  u16* PW = Pl + wv * 1024;

  auto ldf = [&](const u16* p) { return *reinterpret_cast<const bf16x8*>(p); };

#pragma unroll
  for (int rt = 0; rt < 2; ++rt) {
    // Q fragments for this 16-row tile, direct from global
    const int tq = 32 * wv + 16 * rt + ro;
    const size_t qbase = ((size_t)(b * LL + lrow(tq))) * 512 + h * 64 + g4 * 8;
    const bf16x8 qf0 = *reinterpret_cast<const bf16x8*>(qp + qbase);
    const bf16x8 qf1 = *reinterpret_cast<const bf16x8*>(qp + qbase + 32);

    // S = Q K^T : 16 q-rows x 256 keys; K frags from swizzled LDS
    f32x4 sa[16] = {};
    __builtin_amdgcn_s_setprio(1);
#pragma unroll
    for (int ct = 0; ct < 16; ++ct) {
      bf16x8 kf0 = ldf(Kl + (16 * ct + ro) * 64 + swA);
      bf16x8 kf1 = ldf(Kl + (16 * ct + ro) * 64 + swB);
      sa[ct] = __builtin_amdgcn_mfma_f32_16x16x32_bf16(qf0, kf0, sa[ct], 0, 0, 0);
      sa[ct] = __builtin_amdgcn_mfma_f32_16x16x32_bf16(qf1, kf1, sa[ct], 0, 0, 0);
    }
    __builtin_amdgcn_s_setprio(0);

    // softmax per q-row (row = g4*4 + j, key = 16*ct + ro)
#pragma unroll
    for (int j = 0; j < 4; ++j) {
      float m = -1e30f;
#pragma unroll
      for (int ct = 0; ct < 16; ++ct) m = fmaxf(m, sa[ct][j]);
      m = fmaxf(m, __shfl_xor(m, 1));
      m = fmaxf(m, __shfl_xor(m, 2));
      m = fmaxf(m, __shfl_xor(m, 4));
      m = fmaxf(m, __shfl_xor(m, 8));
      m *= scale;
      float s = 0.f;
#pragma unroll
      for (int ct = 0; ct < 16; ++ct) {
        float p = __expf(sa[ct][j] * scale - m);
        sa[ct][j] = p;
        s += p;
      }
      s += __shfl_xor(s, 1);
      s += __shfl_xor(s, 2);
      s += __shfl_xor(s, 4);
      s += __shfl_xor(s, 8);
      float inv = 1.f / s;
#pragma unroll
      for (int ct = 0; ct < 16; ++ct) sa[ct][j] *= inv;
    }

    // O = P V in four key-quarters through the per-wave swizzled LDS P tile.
    // In-wave DS ordering makes write->read->overwrite safe without barriers.
    f32x4 oacc[4] = {};
#pragma unroll
    for (int kh = 0; kh < 4; ++kh) {
#pragma unroll
      for (int c = 0; c < 4; ++c)
#pragma unroll
        for (int j = 0; j < 4; ++j) {
          int rq = g4 * 4 + j;
          PW[rq * 64 + (((2 * c + (ro >> 3)) ^ (rq & 7)) * 8) + (ro & 7)] =
              f2bf(sa[kh * 4 + c][j]);
        }
      __builtin_amdgcn_s_setprio(1);
#pragma unroll
      for (int ks = 0; ks < 2; ++ks) {
        bf16x8 pf = ldf(PW + ro * 64 + (((ks * 4 + g4) ^ (ro & 7)) * 8));
        const int kkg = kh * 2 + ks;
#pragma unroll
        for (int cd = 0; cd < 4; ++cd) {
          bf16x8 vf = ldf(Vt + (16 * cd + ro) * 256 + (((kkg * 4 + g4) ^ (ro & 7)) * 8));
          oacc[cd] = __builtin_amdgcn_mfma_f32_16x16x32_bf16(pf, vf, oacc[cd], 0, 0, 0);
        }
      }
      __builtin_amdgcn_s_setprio(0);
    }

    // write out this 16-row tile
#pragma unroll
    for (int cd = 0; cd < 4; ++cd)
#pragma unroll
      for (int j = 0; j < 4; ++j) {
        int t = 32 * wv + 16 * rt + g4 * 4 + j;
        int d = 16 * cd + ro;
        o[((size_t)(b * LL + lrow(t))) * 512 + h * 64 + d] = f2bf(oacc[cd][j]);
      }
  }
}

// ---------------- launch ----------------
extern "C" void kernel_launch(void* const* d_in, const int* in_sizes, int n_in,
                              void* d_out, int out_size, void* d_ws, size_t ws_size,
                              hipStream_t stream) {
  const float* q = (const float*)d_in[0];
  const float* kv = (const float*)d_in[1];
  const float* Wq = (const float*)d_in[2];
  const float* Wkv = (const float*)d_in[3];
  const float* Wfc = (const float*)d_in[4];
  float* out = (float*)d_out;
  char* ws = (char*)d_ws;

  // workspace layout (bytes)
  u16* o_buf = (u16*)(ws + 0);            // 67108864
  u16* qp    = (u16*)(ws + 134217728);    // 67108864
  u16* kvp   = (u16*)(ws + 201326592);    // 134217728
  u16* Wq_t  = (u16*)(ws + 335544320);    // 524288
  u16* Wkv_t = (u16*)(ws + 336068608);    // 1048576
  u16* Wfc_t = (u16*)(ws + 337117184);    // 524288

  tcvt3_kernel<<<4096, 256, 0, stream>>>(Wq, Wkv, Wfc, Wq_t, Wkv_t, Wfc_t);

  gemm256<true, false><<<(MM / 256) * (CC / 256), 512, 0, stream>>>(q, Wq_t, qp, MM, CC, CC);
  gemm256<true, false><<<(MM / 256) * (2 * CC / 256), 512, 0, stream>>>(kv, Wkv_t, kvp, MM, 2 * CC, CC);

  attn_kernel<<<BB * 64 * 8, 512, 0, stream>>>(qp, kvp, o_buf);

  gemm256<false, true><<<(MM / 256) * (CC / 256), 512, 0, stream>>>(o_buf, Wfc_t, out, MM, CC, CC);
}

// Round 8
// 367.666 us; speedup vs baseline: 1.0441x; 1.0441x over previous
//
#include <hip/hip_runtime.h>
#include <stdint.h>

#define BB 4
#define LL 16384
#define CC 512
#define MM (BB * LL)  // 65536

typedef unsigned short u16;
typedef __bf16 bf16x8 __attribute__((ext_vector_type(8)));
typedef float f32x4 __attribute__((ext_vector_type(4)));
typedef u16 u16x8 __attribute__((ext_vector_type(8)));
typedef u16 u16x4 __attribute__((ext_vector_type(4)));

__device__ __forceinline__ u16 f2bf(float f) {
  return __builtin_bit_cast(u16, (__bf16)f);
}

__device__ __forceinline__ void gl_lds16(const void* g, void* l) {
  __builtin_amdgcn_global_load_lds((const __attribute__((address_space(1))) void*)g,
                                   (__attribute__((address_space(3))) void*)l,
                                   16, 0, 0);
}

// ---------------- fp32 -> bf16 convert: 8 elems/thread, 16B stores ----------------
// blocks 0..2047 -> q, 2048..4095 -> kv (uniform per-block select, no divergence)
__global__ void cvt2_kernel(const float* __restrict__ q, const float* __restrict__ kv,
                            u16* __restrict__ qo, u16* __restrict__ kvo, int n8) {
  const int half = blockIdx.x >> 11;
  const float* src = half ? kv : q;
  u16* dst = half ? kvo : qo;
  const int stride = 2048 * blockDim.x;
  for (int i = (blockIdx.x & 2047) * blockDim.x + threadIdx.x; i < n8; i += stride) {
    f32x4 a = reinterpret_cast<const f32x4*>(src)[2 * i];
    f32x4 b = reinterpret_cast<const f32x4*>(src)[2 * i + 1];
    u16x8 o;
    o[0] = f2bf(a[0]); o[1] = f2bf(a[1]); o[2] = f2bf(a[2]); o[3] = f2bf(a[3]);
    o[4] = f2bf(b[0]); o[5] = f2bf(b[1]); o[6] = f2bf(b[2]); o[7] = f2bf(b[3]);
    reinterpret_cast<u16x8*>(dst)[i] = o;
  }
}

// ------- weight transpose+convert via 64x64 LDS tiles: W[K][N] -> Wt[N][K] bf16 -------
// grid 256 blocks x 256 threads. Blocks 0-63: Wq (8x8 tiles), 64-191: Wkv (8x16),
// 192-255: Wfc. Coalesced float4 reads, coalesced u16x8 writes.
__global__ void tcvt3_kernel(const float* __restrict__ Wq, const float* __restrict__ Wkv,
                             const float* __restrict__ Wfc, u16* __restrict__ Wq_t,
                             u16* __restrict__ Wkv_t, u16* __restrict__ Wfc_t) {
  __shared__ float tile[64][65];
  const int bid = blockIdx.x, tid = threadIdx.x;
  const float* W; u16* Wt; int N, ti;
  if (bid < 64)       { W = Wq;  Wt = Wq_t;  N = 512;  ti = bid; }
  else if (bid < 192) { W = Wkv; Wt = Wkv_t; N = 1024; ti = bid - 64; }
  else                { W = Wfc; Wt = Wfc_t; N = 512;  ti = bid - 192; }
  const int ntn = N >> 6;            // tiles along N
  const int kt = ti / ntn, nt = ti % ntn;
  const int k0 = kt << 6, n0 = nt << 6;

  // load 64x64 tile: thread (r = tid>>4, c4 = tid&15); 4 row-groups
  {
    const int r = tid >> 4, c4 = tid & 15;
#pragma unroll
    for (int e = 0; e < 4; ++e) {
      int row = r + e * 16;
      f32x4 v = *reinterpret_cast<const f32x4*>(&W[(size_t)(k0 + row) * N + n0 + c4 * 4]);
      tile[row][c4 * 4 + 0] = v[0]; tile[row][c4 * 4 + 1] = v[1];
      tile[row][c4 * 4 + 2] = v[2]; tile[row][c4 * 4 + 3] = v[3];
    }
  }
  __syncthreads();

  // write transposed: thread (n = tid>>2, q = tid&3) writes 2 u16x8 chunks of row n
  {
    const int n = tid >> 2, qd = tid & 3;
#pragma unroll
    for (int e = 0; e < 2; ++e) {
      int c = qd * 2 + e;  // chunk 0..7 -> k offset c*8
      u16x8 o;
#pragma unroll
      for (int j = 0; j < 8; ++j) o[j] = f2bf(tile[c * 8 + j][n]);
      *reinterpret_cast<u16x8*>(&Wt[(size_t)(n0 + n) * 512 + k0 + c * 8]) = o;
    }
  }
}

// ---------------- 256x256 8-phase NT GEMM: C[M][N] = A[M][K] * Bt[N][K]^T ----------
// BM=BN=256, BK=64, 8 waves (2M x 4N), double-buffered LDS, T2 XOR-swizzle,
// counted vmcnt, setprio around MFMA clusters. K must be a multiple of 128.
// Stage discipline: a gl_lds may only target a region whose last reads are
// closed by an end-of-phase barrier. A reads span all 4 phases -> A(u+1) is
// staged into the opposite-parity (idle) buffer @p1/p2. B reads are all in
// phase 1 -> B(u+2) staged into same-parity buffer @p3/p4. vmcnt(4) per tile.
template <bool OUT_F32>
__global__ __launch_bounds__(512, 2) void gemm256(const u16* __restrict__ A,
                                                  const u16* __restrict__ Bt,
                                                  void* __restrict__ Cp,
                                                  int M, int N, int K) {
  __shared__ __align__(16) u16 Al[2][16384];
  __shared__ __align__(16) u16 Bl[2][16384];
  const int nbn = N >> 8;
  const int nwg = gridDim.x;
  const int bid0 = blockIdx.x;
  const int cpx = nwg >> 3;  // grid % 8 == 0 for all our shapes
  const int bid = (bid0 & 7) * cpx + (bid0 >> 3);
  const int bm = bid / nbn, bn = bid % nbn;
  const size_t row0 = (size_t)bm << 8, col0 = (size_t)bn << 8;
  const int tid = threadIdx.x, lane = tid & 63;
  const int wv = tid >> 6, wm = wv >> 2, wn = wv & 3;
  const int ro = lane & 15, g4 = lane >> 4;
  const int NT = K >> 6;

  // staging geometry: chunk ci covers (row=ci>>3, colgroup=ci&7) of a 128x64 half-tile.
  // LDS dest is LINEAR; global source colgroup pre-swizzled: gg = g ^ (row&7).
  const int ci0 = tid, ci1 = tid + 512;
  const int r0 = ci0 >> 3, g0 = (ci0 & 7) ^ (r0 & 7);
  const int r1 = ci1 >> 3, g1 = (ci1 & 7) ^ (r1 & 7);

  auto stageA = [&](int half, int kt, u16* L) {
    gl_lds16(A + (row0 + half * 128 + r0) * (size_t)K + kt * 64 + g0 * 8, L + half * 8192 + ci0 * 8);
    gl_lds16(A + (row0 + half * 128 + r1) * (size_t)K + kt * 64 + g1 * 8, L + half * 8192 + ci1 * 8);
  };
  auto stageB = [&](int half, int kt, u16* L) {
    gl_lds16(Bt + (col0 + half * 128 + r0) * (size_t)K + kt * 64 + g0 * 8, L + half * 8192 + ci0 * 8);
    gl_lds16(Bt + (col0 + half * 128 + r1) * (size_t)K + kt * 64 + g1 * 8, L + half * 8192 + ci1 * 8);
  };

  // ds_read offsets (u16 elements), swizzled: phys colgroup = logical ^ (row&7)
  const int aB = (wm * 128 + ro) * 64;
  const int bB = (wn * 64 + ro) * 64;
  const int sw0 = (g4 ^ (ro & 7)) * 8;
  const int sw1 = ((g4 + 4) ^ (ro & 7)) * 8;

  auto ldf = [&](const u16* p) { return *reinterpret_cast<const bf16x8*>(p); };

  f32x4 acc[8][4] = {};

  // prologue: tile 0 fully + B of tile 1. Queue: [A(0)^4, B(0)^4, B(1)^4].
  stageA(0, 0, Al[0]); stageA(1, 0, Al[0]); stageB(0, 0, Bl[0]); stageB(1, 0, Bl[0]);
  stageB(0, 1, Bl[1]); stageB(1, 1, Bl[1]);
  asm volatile("s_waitcnt vmcnt(4)" ::: "memory");  // drain A(0)+B(0); B(1) in flight
  __builtin_amdgcn_s_barrier();

  for (int t = 0; t < NT; t += 2) {
#pragma unroll
    for (int half = 0; half < 2; ++half) {
      const int u = t + half;
      u16* LA = Al[half];
      u16* LB = Bl[half];
      u16* LAn = Al[half ^ 1];
      const bool stA = (u + 1) < NT;
      const bool stB = (u + 2) < NT;
      bf16x8 bfr[4][2], af[2][2];

      // ---- phase 1: all B frags + A m0,m1; stage A half0 (u+1) into idle buffer ----
#pragma unroll
      for (int n = 0; n < 4; ++n) {
        bfr[n][0] = ldf(LB + bB + n * 1024 + sw0);
        bfr[n][1] = ldf(LB + bB + n * 1024 + sw1);
      }
      af[0][0] = ldf(LA + aB + sw0);        af[0][1] = ldf(LA + aB + sw1);
      af[1][0] = ldf(LA + aB + 1024 + sw0); af[1][1] = ldf(LA + aB + 1024 + sw1);
      if (stA) stageA(0, u + 1, LAn);
      __builtin_amdgcn_s_barrier();
      asm volatile("s_waitcnt lgkmcnt(0)" ::: "memory");
      __builtin_amdgcn_sched_barrier(0);
      __builtin_amdgcn_s_setprio(1);
#pragma unroll
      for (int m = 0; m < 2; ++m)
#pragma unroll
        for (int n = 0; n < 4; ++n) {
          acc[m][n] = __builtin_amdgcn_mfma_f32_16x16x32_bf16(af[m][0], bfr[n][0], acc[m][n], 0, 0, 0);
          acc[m][n] = __builtin_amdgcn_mfma_f32_16x16x32_bf16(af[m][1], bfr[n][1], acc[m][n], 0, 0, 0);
        }
      __builtin_amdgcn_s_setprio(0);
      __builtin_amdgcn_s_barrier();

      // ---- phases 2..4: A m=2ph..2ph+1; stage Ah1(u+1) / Bh0(u+2) / Bh1(u+2) ----
#pragma unroll
      for (int ph = 1; ph < 4; ++ph) {
        af[0][0] = ldf(LA + aB + (2 * ph) * 1024 + sw0);
        af[0][1] = ldf(LA + aB + (2 * ph) * 1024 + sw1);
        af[1][0] = ldf(LA + aB + (2 * ph + 1) * 1024 + sw0);
        af[1][1] = ldf(LA + aB + (2 * ph + 1) * 1024 + sw1);
        if (ph == 1) { if (stA) stageA(1, u + 1, LAn); }
        else if (ph == 2) { if (stB) stageB(0, u + 2, LB); }
        else { if (stB) stageB(1, u + 2, LB); }
        __builtin_amdgcn_s_barrier();
        asm volatile("s_waitcnt lgkmcnt(0)" ::: "memory");
        __builtin_amdgcn_sched_barrier(0);
        __builtin_amdgcn_s_setprio(1);
#pragma unroll
        for (int m = 0; m < 2; ++m)
#pragma unroll
          for (int n = 0; n < 4; ++n) {
            acc[2 * ph + m][n] =
                __builtin_amdgcn_mfma_f32_16x16x32_bf16(af[m][0], bfr[n][0], acc[2 * ph + m][n], 0, 0, 0);
            acc[2 * ph + m][n] =
                __builtin_amdgcn_mfma_f32_16x16x32_bf16(af[m][1], bfr[n][1], acc[2 * ph + m][n], 0, 0, 0);
          }
        __builtin_amdgcn_s_setprio(0);
        if (ph == 3) {
          if (stB) asm volatile("s_waitcnt vmcnt(4)" ::: "memory");
          else     asm volatile("s_waitcnt vmcnt(0)" ::: "memory");
        }
        __builtin_amdgcn_s_barrier();
      }
    }
  }

  // epilogue: C write
#pragma unroll
  for (int m = 0; m < 8; ++m)
#pragma unroll
    for (int n = 0; n < 4; ++n)
#pragma unroll
      for (int j = 0; j < 4; ++j) {
        size_t r = row0 + wm * 128 + m * 16 + g4 * 4 + j;
        size_t c = col0 + wn * 64 + n * 16 + ro;
        if (OUT_F32)
          reinterpret_cast<float*>(Cp)[r * N + c] = acc[m][n][j];
        else
          reinterpret_cast<u16*>(Cp)[r * N + c] = f2bf(acc[m][n][j]);
      }
}

// ---------------- window attention ----------------
// grid: b*512 + w*8 + h  (2048 blocks), 512 threads (8 waves, 32 q-rows each).
// K in LDS via global_load_lds with pre-swizzled source (32KB); V transposed in
// LDS, XOR-swizzled (32KB); P per-wave quarter-split, XOR-swizzled (16KB).
// Total exactly 80KB -> 2 blocks/CU.
__global__ __launch_bounds__(512, 4) void attn_kernel(const u16* __restrict__ qp,
                                                      const u16* __restrict__ kvp,
                                                      u16* __restrict__ o) {
  __shared__ __align__(16) u16 Kl[256 * 64];
  __shared__ __align__(16) u16 Vt[64 * 256];
  __shared__ __align__(16) u16 Pl[8 * 1024];
  const int bid = blockIdx.x;
  const int h = bid & 7, w = (bid >> 3) & 63, b = bid >> 9;
  const int w1 = w >> 3, w2 = w & 7;
  const int tid = threadIdx.x, lane = tid & 63, wv = tid >> 6;

  auto lrow = [&](int t) { return (w1 * 16 + (t >> 4)) * 128 + w2 * 16 + (t & 15); };

  // stage K: 2048 16B chunks; chunk ci = (row r = ci>>3, colgroup g = ci&7).
  // LDS dest linear; global source colgroup pre-swizzled g^(r&7).
#pragma unroll
  for (int p = 0; p < 4; ++p) {
    int ci = tid + p * 512;
    int r = ci >> 3, g = (ci & 7) ^ (r & 7);
    gl_lds16(kvp + ((size_t)(b * LL + lrow(r))) * 1024 + h * 64 + g * 8, Kl + ci * 8);
  }
  // stage V transposed, swizzled: logical (d, tk) at phys d*256 + ((tk>>3)^(d&7))*8 + (tk&7)
  {
    const int tk = tid >> 1, half = tid & 1;
    const size_t base = ((size_t)(b * LL + lrow(tk))) * 1024 + 512 + h * 64 + half * 32;
#pragma unroll
    for (int c = 0; c < 4; ++c) {
      u16x8 vx = *reinterpret_cast<const u16x8*>(kvp + base + c * 8);
#pragma unroll
      for (int e = 0; e < 8; ++e) {
        int d = half * 32 + c * 8 + e;
        Vt[d * 256 + (((tk >> 3) ^ (d & 7)) * 8) + (tk & 7)] = vx[e];
      }
    }
  }
  __syncthreads();

  const int ro = lane & 15;       // low nibble
  const int g4 = lane >> 4;       // lane group 0..3
  const float scale = 0.125f;     // hd^-0.5, hd=64
  const int swA = (g4 ^ (ro & 7)) * 8;
  const int swB = ((g4 + 4) ^ (ro & 7)) * 8;
  u16* PW = Pl + wv * 1024;

  auto ldf = [&](const u16* p) { return *reinterpret_cast<const bf16x8*>(p); };

#pragma unroll
  for (int rt = 0; rt < 2; ++rt) {
    // Q fragments for this 16-row tile, direct from global
    const int tq = 32 * wv + 16 * rt + ro;
    const size_t qbase = ((size_t)(b * LL + lrow(tq))) * 512 + h * 64 + g4 * 8;
    const bf16x8 qf0 = *reinterpret_cast<const bf16x8*>(qp + qbase);
    const bf16x8 qf1 = *reinterpret_cast<const bf16x8*>(qp + qbase + 32);

    // S = Q K^T : 16 q-rows x 256 keys; K frags from swizzled LDS
    f32x4 sa[16] = {};
    __builtin_amdgcn_s_setprio(1);
#pragma unroll
    for (int ct = 0; ct < 16; ++ct) {
      bf16x8 kf0 = ldf(Kl + (16 * ct + ro) * 64 + swA);
      bf16x8 kf1 = ldf(Kl + (16 * ct + ro) * 64 + swB);
      sa[ct] = __builtin_amdgcn_mfma_f32_16x16x32_bf16(qf0, kf0, sa[ct], 0, 0, 0);
      sa[ct] = __builtin_amdgcn_mfma_f32_16x16x32_bf16(qf1, kf1, sa[ct], 0, 0, 0);
    }
    __builtin_amdgcn_s_setprio(0);

    // softmax per q-row (row = g4*4 + j, key = 16*ct + ro)
#pragma unroll
    for (int j = 0; j < 4; ++j) {
      float m = -1e30f;
#pragma unroll
      for (int ct = 0; ct < 16; ++ct) m = fmaxf(m, sa[ct][j]);
      m = fmaxf(m, __shfl_xor(m, 1));
      m = fmaxf(m, __shfl_xor(m, 2));
      m = fmaxf(m, __shfl_xor(m, 4));
      m = fmaxf(m, __shfl_xor(m, 8));
      m *= scale;
      float s = 0.f;
#pragma unroll
      for (int ct = 0; ct < 16; ++ct) {
        float p = __expf(sa[ct][j] * scale - m);
        sa[ct][j] = p;
        s += p;
      }
      s += __shfl_xor(s, 1);
      s += __shfl_xor(s, 2);
      s += __shfl_xor(s, 4);
      s += __shfl_xor(s, 8);
      float inv = 1.f / s;
#pragma unroll
      for (int ct = 0; ct < 16; ++ct) sa[ct][j] *= inv;
    }

    // O = P V in four key-quarters through the per-wave swizzled LDS P tile.
    // In-wave DS ordering makes write->read->overwrite safe without barriers.
    f32x4 oacc[4] = {};
#pragma unroll
    for (int kh = 0; kh < 4; ++kh) {
#pragma unroll
      for (int c = 0; c < 4; ++c)
#pragma unroll
        for (int j = 0; j < 4; ++j) {
          int rq = g4 * 4 + j;
          PW[rq * 64 + (((2 * c + (ro >> 3)) ^ (rq & 7)) * 8) + (ro & 7)] =
              f2bf(sa[kh * 4 + c][j]);
        }
      __builtin_amdgcn_s_setprio(1);
#pragma unroll
      for (int ks = 0; ks < 2; ++ks) {
        bf16x8 pf = ldf(PW + ro * 64 + (((ks * 4 + g4) ^ (ro & 7)) * 8));
        const int kkg = kh * 2 + ks;
#pragma unroll
        for (int cd = 0; cd < 4; ++cd) {
          bf16x8 vf = ldf(Vt + (16 * cd + ro) * 256 + (((kkg * 4 + g4) ^ (ro & 7)) * 8));
          oacc[cd] = __builtin_amdgcn_mfma_f32_16x16x32_bf16(pf, vf, oacc[cd], 0, 0, 0);
        }
      }
      __builtin_amdgcn_s_setprio(0);
    }

    // write out this 16-row tile
#pragma unroll
    for (int cd = 0; cd < 4; ++cd)
#pragma unroll
      for (int j = 0; j < 4; ++j) {
        int t = 32 * wv + 16 * rt + g4 * 4 + j;
        int d = 16 * cd + ro;
        o[((size_t)(b * LL + lrow(t))) * 512 + h * 64 + d] = f2bf(oacc[cd][j]);
      }
  }
}

// ---------------- launch ----------------
extern "C" void kernel_launch(void* const* d_in, const int* in_sizes, int n_in,
                              void* d_out, int out_size, void* d_ws, size_t ws_size,
                              hipStream_t stream) {
  const float* q = (const float*)d_in[0];
  const float* kv = (const float*)d_in[1];
  const float* Wq = (const float*)d_in[2];
  const float* Wkv = (const float*)d_in[3];
  const float* Wfc = (const float*)d_in[4];
  float* out = (float*)d_out;
  char* ws = (char*)d_ws;

  // workspace layout (bytes)
  u16* q_bf  = (u16*)(ws + 0);            // 67108864  (also reused as o_buf)
  u16* kv_bf = (u16*)(ws + 67108864);     // 67108864
  u16* qp    = (u16*)(ws + 134217728);    // 67108864
  u16* kvp   = (u16*)(ws + 201326592);    // 134217728
  u16* Wq_t  = (u16*)(ws + 335544320);    // 524288
  u16* Wkv_t = (u16*)(ws + 336068608);    // 1048576
  u16* Wfc_t = (u16*)(ws + 337117184);    // 524288
  u16* o_buf = q_bf;                      // q_bf dead after GEMM1

  const int n8 = MM * CC / 8;  // 4194304 groups of 8 per array
  cvt2_kernel<<<4096, 256, 0, stream>>>(q, kv, q_bf, kv_bf, n8);
  tcvt3_kernel<<<256, 256, 0, stream>>>(Wq, Wkv, Wfc, Wq_t, Wkv_t, Wfc_t);

  gemm256<false><<<(MM / 256) * (CC / 256), 512, 0, stream>>>(q_bf, Wq_t, qp, MM, CC, CC);
  gemm256<false><<<(MM / 256) * (2 * CC / 256), 512, 0, stream>>>(kv_bf, Wkv_t, kvp, MM, 2 * CC, CC);

  attn_kernel<<<BB * 64 * 8, 512, 0, stream>>>(qp, kvp, o_buf);

  gemm256<true><<<(MM / 256) * (CC / 256), 512, 0, stream>>>(o_buf, Wfc_t, out, MM, CC, CC);
}

// Round 9
// 365.509 us; speedup vs baseline: 1.0503x; 1.0059x over previous
//
#include <hip/hip_runtime.h>
#include <stdint.h>

#define BB 4
#define LL 16384
#define CC 512
#define MM (BB * LL)  // 65536

typedef unsigned short u16;
typedef __bf16 bf16x8 __attribute__((ext_vector_type(8)));
typedef float f32x4 __attribute__((ext_vector_type(4)));
typedef u16 u16x8 __attribute__((ext_vector_type(8)));
typedef u16 u16x4 __attribute__((ext_vector_type(4)));

__device__ __forceinline__ u16 f2bf(float f) {
  return __builtin_bit_cast(u16, (__bf16)f);
}

__device__ __forceinline__ void gl_lds16(const void* g, void* l) {
  __builtin_amdgcn_global_load_lds((const __attribute__((address_space(1))) void*)g,
                                   (__attribute__((address_space(3))) void*)l,
                                   16, 0, 0);
}

// ---------------- fused prep: fp32->bf16 cvt (q,kv) + weight transpose-cvt ----------
// blocks 0..2047: q cvt; 2048..4095: kv cvt (16 elems/thread/iter -> 4 loads in
// flight, latency-covered); 4096..4351: 64x64 LDS-tile weight transpose.
__global__ __launch_bounds__(256) void prep_kernel(
    const float* __restrict__ q, const float* __restrict__ kv,
    const float* __restrict__ Wq, const float* __restrict__ Wkv,
    const float* __restrict__ Wfc, u16* __restrict__ qo, u16* __restrict__ kvo,
    u16* __restrict__ Wq_t, u16* __restrict__ Wkv_t, u16* __restrict__ Wfc_t) {
  __shared__ float tile[64][65];
  const int bid = blockIdx.x, tid = threadIdx.x;

  if (bid < 4096) {
    const int half = bid >> 11;
    const float* src = half ? kv : q;
    u16* dst = half ? kvo : qo;
    const int n16 = MM * CC / 16;  // 2097152
    const int stride = 2048 * 256;
    for (int i = (bid & 2047) * 256 + tid; i < n16; i += stride) {
      f32x4 a0 = reinterpret_cast<const f32x4*>(src)[4 * i + 0];
      f32x4 a1 = reinterpret_cast<const f32x4*>(src)[4 * i + 1];
      f32x4 a2 = reinterpret_cast<const f32x4*>(src)[4 * i + 2];
      f32x4 a3 = reinterpret_cast<const f32x4*>(src)[4 * i + 3];
      u16x8 o0, o1;
      o0[0] = f2bf(a0[0]); o0[1] = f2bf(a0[1]); o0[2] = f2bf(a0[2]); o0[3] = f2bf(a0[3]);
      o0[4] = f2bf(a1[0]); o0[5] = f2bf(a1[1]); o0[6] = f2bf(a1[2]); o0[7] = f2bf(a1[3]);
      o1[0] = f2bf(a2[0]); o1[1] = f2bf(a2[1]); o1[2] = f2bf(a2[2]); o1[3] = f2bf(a2[3]);
      o1[4] = f2bf(a3[0]); o1[5] = f2bf(a3[1]); o1[6] = f2bf(a3[2]); o1[7] = f2bf(a3[3]);
      reinterpret_cast<u16x8*>(dst)[2 * i + 0] = o0;
      reinterpret_cast<u16x8*>(dst)[2 * i + 1] = o1;
    }
    return;
  }

  // weight transpose: W[K][N] -> Wt[N][K] bf16, 64x64 tiles
  const int wb = bid - 4096;
  const float* W; u16* Wt; int N, ti;
  if (wb < 64)       { W = Wq;  Wt = Wq_t;  N = 512;  ti = wb; }
  else if (wb < 192) { W = Wkv; Wt = Wkv_t; N = 1024; ti = wb - 64; }
  else               { W = Wfc; Wt = Wfc_t; N = 512;  ti = wb - 192; }
  const int ntn = N >> 6;
  const int kt = ti / ntn, nt = ti % ntn;
  const int k0 = kt << 6, n0 = nt << 6;
  {
    const int r = tid >> 4, c4 = tid & 15;
#pragma unroll
    for (int e = 0; e < 4; ++e) {
      int row = r + e * 16;
      f32x4 v = *reinterpret_cast<const f32x4*>(&W[(size_t)(k0 + row) * N + n0 + c4 * 4]);
      tile[row][c4 * 4 + 0] = v[0]; tile[row][c4 * 4 + 1] = v[1];
      tile[row][c4 * 4 + 2] = v[2]; tile[row][c4 * 4 + 3] = v[3];
    }
  }
  __syncthreads();
  {
    const int n = tid >> 2, qd = tid & 3;
#pragma unroll
    for (int e = 0; e < 2; ++e) {
      int c = qd * 2 + e;
      u16x8 o;
#pragma unroll
      for (int j = 0; j < 8; ++j) o[j] = f2bf(tile[c * 8 + j][n]);
      *reinterpret_cast<u16x8*>(&Wt[(size_t)(n0 + n) * 512 + k0 + c * 8]) = o;
    }
  }
}

// ---------------- 256x256 8-phase NT GEMM: C[M][N] = A[M][K] * Bt[N][K]^T ----------
// BM=BN=256, BK=64, 8 waves (2M x 4N), double-buffered LDS, T2 XOR-swizzle,
// counted vmcnt, setprio around MFMA clusters. K must be a multiple of 128.
// Stage discipline: a gl_lds may only target a region whose last reads are
// closed by an end-of-phase barrier. A reads span all 4 phases -> A(u+1) is
// staged into the opposite-parity (idle) buffer @p1/p2. B reads are all in
// phase 1 -> B(u+2) staged into same-parity buffer @p3/p4. vmcnt(4) per tile.
template <bool OUT_F32>
__global__ __launch_bounds__(512, 2) void gemm256(const u16* __restrict__ A,
                                                  const u16* __restrict__ Bt,
                                                  void* __restrict__ Cp,
                                                  int M, int N, int K) {
  __shared__ __align__(16) u16 Al[2][16384];
  __shared__ __align__(16) u16 Bl[2][16384];
  const int nbn = N >> 8;
  const int nwg = gridDim.x;
  const int bid0 = blockIdx.x;
  const int cpx = nwg >> 3;  // grid % 8 == 0 for all our shapes
  const int bid = (bid0 & 7) * cpx + (bid0 >> 3);
  const int bm = bid / nbn, bn = bid % nbn;
  const size_t row0 = (size_t)bm << 8, col0 = (size_t)bn << 8;
  const int tid = threadIdx.x, lane = tid & 63;
  const int wv = tid >> 6, wm = wv >> 2, wn = wv & 3;
  const int ro = lane & 15, g4 = lane >> 4;
  const int NT = K >> 6;

  // staging geometry: chunk ci covers (row=ci>>3, colgroup=ci&7) of a 128x64 half-tile.
  // LDS dest is LINEAR; global source colgroup pre-swizzled: gg = g ^ (row&7).
  const int ci0 = tid, ci1 = tid + 512;
  const int r0 = ci0 >> 3, g0 = (ci0 & 7) ^ (r0 & 7);
  const int r1 = ci1 >> 3, g1 = (ci1 & 7) ^ (r1 & 7);

  auto stageA = [&](int half, int kt, u16* L) {
    gl_lds16(A + (row0 + half * 128 + r0) * (size_t)K + kt * 64 + g0 * 8, L + half * 8192 + ci0 * 8);
    gl_lds16(A + (row0 + half * 128 + r1) * (size_t)K + kt * 64 + g1 * 8, L + half * 8192 + ci1 * 8);
  };
  auto stageB = [&](int half, int kt, u16* L) {
    gl_lds16(Bt + (col0 + half * 128 + r0) * (size_t)K + kt * 64 + g0 * 8, L + half * 8192 + ci0 * 8);
    gl_lds16(Bt + (col0 + half * 128 + r1) * (size_t)K + kt * 64 + g1 * 8, L + half * 8192 + ci1 * 8);
  };

  // ds_read offsets (u16 elements), swizzled: phys colgroup = logical ^ (row&7)
  const int aB = (wm * 128 + ro) * 64;
  const int bB = (wn * 64 + ro) * 64;
  const int sw0 = (g4 ^ (ro & 7)) * 8;
  const int sw1 = ((g4 + 4) ^ (ro & 7)) * 8;

  auto ldf = [&](const u16* p) { return *reinterpret_cast<const bf16x8*>(p); };

  f32x4 acc[8][4] = {};

  // prologue: tile 0 fully + B of tile 1. Queue: [A(0)^4, B(0)^4, B(1)^4].
  stageA(0, 0, Al[0]); stageA(1, 0, Al[0]); stageB(0, 0, Bl[0]); stageB(1, 0, Bl[0]);
  stageB(0, 1, Bl[1]); stageB(1, 1, Bl[1]);
  asm volatile("s_waitcnt vmcnt(4)" ::: "memory");  // drain A(0)+B(0); B(1) in flight
  __builtin_amdgcn_s_barrier();

  for (int t = 0; t < NT; t += 2) {
#pragma unroll
    for (int half = 0; half < 2; ++half) {
      const int u = t + half;
      u16* LA = Al[half];
      u16* LB = Bl[half];
      u16* LAn = Al[half ^ 1];
      const bool stA = (u + 1) < NT;
      const bool stB = (u + 2) < NT;
      bf16x8 bfr[4][2], af[2][2];

      // ---- phase 1: all B frags + A m0,m1; stage A half0 (u+1) into idle buffer ----
#pragma unroll
      for (int n = 0; n < 4; ++n) {
        bfr[n][0] = ldf(LB + bB + n * 1024 + sw0);
        bfr[n][1] = ldf(LB + bB + n * 1024 + sw1);
      }
      af[0][0] = ldf(LA + aB + sw0);        af[0][1] = ldf(LA + aB + sw1);
      af[1][0] = ldf(LA + aB + 1024 + sw0); af[1][1] = ldf(LA + aB + 1024 + sw1);
      if (stA) stageA(0, u + 1, LAn);
      __builtin_amdgcn_s_barrier();
      asm volatile("s_waitcnt lgkmcnt(0)" ::: "memory");
      __builtin_amdgcn_sched_barrier(0);
      __builtin_amdgcn_s_setprio(1);
#pragma unroll
      for (int m = 0; m < 2; ++m)
#pragma unroll
        for (int n = 0; n < 4; ++n) {
          acc[m][n] = __builtin_amdgcn_mfma_f32_16x16x32_bf16(af[m][0], bfr[n][0], acc[m][n], 0, 0, 0);
          acc[m][n] = __builtin_amdgcn_mfma_f32_16x16x32_bf16(af[m][1], bfr[n][1], acc[m][n], 0, 0, 0);
        }
      __builtin_amdgcn_s_setprio(0);
      __builtin_amdgcn_s_barrier();

      // ---- phases 2..4: A m=2ph..2ph+1; stage Ah1(u+1) / Bh0(u+2) / Bh1(u+2) ----
#pragma unroll
      for (int ph = 1; ph < 4; ++ph) {
        af[0][0] = ldf(LA + aB + (2 * ph) * 1024 + sw0);
        af[0][1] = ldf(LA + aB + (2 * ph) * 1024 + sw1);
        af[1][0] = ldf(LA + aB + (2 * ph + 1) * 1024 + sw0);
        af[1][1] = ldf(LA + aB + (2 * ph + 1) * 1024 + sw1);
        if (ph == 1) { if (stA) stageA(1, u + 1, LAn); }
        else if (ph == 2) { if (stB) stageB(0, u + 2, LB); }
        else { if (stB) stageB(1, u + 2, LB); }
        __builtin_amdgcn_s_barrier();
        asm volatile("s_waitcnt lgkmcnt(0)" ::: "memory");
        __builtin_amdgcn_sched_barrier(0);
        __builtin_amdgcn_s_setprio(1);
#pragma unroll
        for (int m = 0; m < 2; ++m)
#pragma unroll
          for (int n = 0; n < 4; ++n) {
            acc[2 * ph + m][n] =
                __builtin_amdgcn_mfma_f32_16x16x32_bf16(af[m][0], bfr[n][0], acc[2 * ph + m][n], 0, 0, 0);
            acc[2 * ph + m][n] =
                __builtin_amdgcn_mfma_f32_16x16x32_bf16(af[m][1], bfr[n][1], acc[2 * ph + m][n], 0, 0, 0);
          }
        __builtin_amdgcn_s_setprio(0);
        if (ph == 3) {
          if (stB) asm volatile("s_waitcnt vmcnt(4)" ::: "memory");
          else     asm volatile("s_waitcnt vmcnt(0)" ::: "memory");
        }
        __builtin_amdgcn_s_barrier();
      }
    }
  }

  // epilogue: C write
#pragma unroll
  for (int m = 0; m < 8; ++m)
#pragma unroll
    for (int n = 0; n < 4; ++n)
#pragma unroll
      for (int j = 0; j < 4; ++j) {
        size_t r = row0 + wm * 128 + m * 16 + g4 * 4 + j;
        size_t c = col0 + wn * 64 + n * 16 + ro;
        if (OUT_F32)
          reinterpret_cast<float*>(Cp)[r * N + c] = acc[m][n][j];
        else
          reinterpret_cast<u16*>(Cp)[r * N + c] = f2bf(acc[m][n][j]);
      }
}

// ---------------- window attention ----------------
// grid: b*512 + w*8 + h  (2048 blocks), 512 threads (8 waves, 32 q-rows each).
// K in LDS via global_load_lds with pre-swizzled source (32KB); V transposed in
// LDS, XOR-swizzled (32KB); P per-wave quarter-split, XOR-swizzled (16KB).
// Total exactly 80KB -> 2 blocks/CU.
__global__ __launch_bounds__(512, 4) void attn_kernel(const u16* __restrict__ qp,
                                                      const u16* __restrict__ kvp,
                                                      u16* __restrict__ o) {
  __shared__ __align__(16) u16 Kl[256 * 64];
  __shared__ __align__(16) u16 Vt[64 * 256];
  __shared__ __align__(16) u16 Pl[8 * 1024];
  const int bid = blockIdx.x;
  const int h = bid & 7, w = (bid >> 3) & 63, b = bid >> 9;
  const int w1 = w >> 3, w2 = w & 7;
  const int tid = threadIdx.x, lane = tid & 63, wv = tid >> 6;

  auto lrow = [&](int t) { return (w1 * 16 + (t >> 4)) * 128 + w2 * 16 + (t & 15); };

  // stage K: 2048 16B chunks; chunk ci = (row r = ci>>3, colgroup g = ci&7).
  // LDS dest linear; global source colgroup pre-swizzled g^(r&7).
#pragma unroll
  for (int p = 0; p < 4; ++p) {
    int ci = tid + p * 512;
    int r = ci >> 3, g = (ci & 7) ^ (r & 7);
    gl_lds16(kvp + ((size_t)(b * LL + lrow(r))) * 1024 + h * 64 + g * 8, Kl + ci * 8);
  }
  // stage V transposed, swizzled: logical (d, tk) at phys d*256 + ((tk>>3)^(d&7))*8 + (tk&7)
  {
    const int tk = tid >> 1, half = tid & 1;
    const size_t base = ((size_t)(b * LL + lrow(tk))) * 1024 + 512 + h * 64 + half * 32;
#pragma unroll
    for (int c = 0; c < 4; ++c) {
      u16x8 vx = *reinterpret_cast<const u16x8*>(kvp + base + c * 8);
#pragma unroll
      for (int e = 0; e < 8; ++e) {
        int d = half * 32 + c * 8 + e;
        Vt[d * 256 + (((tk >> 3) ^ (d & 7)) * 8) + (tk & 7)] = vx[e];
      }
    }
  }
  __syncthreads();

  const int ro = lane & 15;       // low nibble
  const int g4 = lane >> 4;       // lane group 0..3
  const float scale = 0.125f;     // hd^-0.5, hd=64
  const int swA = (g4 ^ (ro & 7)) * 8;
  const int swB = ((g4 + 4) ^ (ro & 7)) * 8;
  u16* PW = Pl + wv * 1024;

  auto ldf = [&](const u16* p) { return *reinterpret_cast<const bf16x8*>(p); };

#pragma unroll
  for (int rt = 0; rt < 2; ++rt) {
    // Q fragments for this 16-row tile, direct from global
    const int tq = 32 * wv + 16 * rt + ro;
    const size_t qbase = ((size_t)(b * LL + lrow(tq))) * 512 + h * 64 + g4 * 8;
    const bf16x8 qf0 = *reinterpret_cast<const bf16x8*>(qp + qbase);
    const bf16x8 qf1 = *reinterpret_cast<const bf16x8*>(qp + qbase + 32);

    // S = Q K^T : 16 q-rows x 256 keys; K frags from swizzled LDS
    f32x4 sa[16] = {};
    __builtin_amdgcn_s_setprio(1);
#pragma unroll
    for (int ct = 0; ct < 16; ++ct) {
      bf16x8 kf0 = ldf(Kl + (16 * ct + ro) * 64 + swA);
      bf16x8 kf1 = ldf(Kl + (16 * ct + ro) * 64 + swB);
      sa[ct] = __builtin_amdgcn_mfma_f32_16x16x32_bf16(qf0, kf0, sa[ct], 0, 0, 0);
      sa[ct] = __builtin_amdgcn_mfma_f32_16x16x32_bf16(qf1, kf1, sa[ct], 0, 0, 0);
    }
    __builtin_amdgcn_s_setprio(0);

    // softmax per q-row (row = g4*4 + j, key = 16*ct + ro)
#pragma unroll
    for (int j = 0; j < 4; ++j) {
      float m = -1e30f;
#pragma unroll
      for (int ct = 0; ct < 16; ++ct) m = fmaxf(m, sa[ct][j]);
      m = fmaxf(m, __shfl_xor(m, 1));
      m = fmaxf(m, __shfl_xor(m, 2));
      m = fmaxf(m, __shfl_xor(m, 4));
      m = fmaxf(m, __shfl_xor(m, 8));
      m *= scale;
      float s = 0.f;
#pragma unroll
      for (int ct = 0; ct < 16; ++ct) {
        float p = __expf(sa[ct][j] * scale - m);
        sa[ct][j] = p;
        s += p;
      }
      s += __shfl_xor(s, 1);
      s += __shfl_xor(s, 2);
      s += __shfl_xor(s, 4);
      s += __shfl_xor(s, 8);
      float inv = 1.f / s;
#pragma unroll
      for (int ct = 0; ct < 16; ++ct) sa[ct][j] *= inv;
    }

    // O = P V in four key-quarters through the per-wave swizzled LDS P tile.
    // In-wave DS ordering makes write->read->overwrite safe without barriers.
    f32x4 oacc[4] = {};
#pragma unroll
    for (int kh = 0; kh < 4; ++kh) {
#pragma unroll
      for (int c = 0; c < 4; ++c)
#pragma unroll
        for (int j = 0; j < 4; ++j) {
          int rq = g4 * 4 + j;
          PW[rq * 64 + (((2 * c + (ro >> 3)) ^ (rq & 7)) * 8) + (ro & 7)] =
              f2bf(sa[kh * 4 + c][j]);
        }
      __builtin_amdgcn_s_setprio(1);
#pragma unroll
      for (int ks = 0; ks < 2; ++ks) {
        bf16x8 pf = ldf(PW + ro * 64 + (((ks * 4 + g4) ^ (ro & 7)) * 8));
        const int kkg = kh * 2 + ks;
#pragma unroll
        for (int cd = 0; cd < 4; ++cd) {
          bf16x8 vf = ldf(Vt + (16 * cd + ro) * 256 + (((kkg * 4 + g4) ^ (ro & 7)) * 8));
          oacc[cd] = __builtin_amdgcn_mfma_f32_16x16x32_bf16(pf, vf, oacc[cd], 0, 0, 0);
        }
      }
      __builtin_amdgcn_s_setprio(0);
    }

    // write out this 16-row tile
#pragma unroll
    for (int cd = 0; cd < 4; ++cd)
#pragma unroll
      for (int j = 0; j < 4; ++j) {
        int t = 32 * wv + 16 * rt + g4 * 4 + j;
        int d = 16 * cd + ro;
        o[((size_t)(b * LL + lrow(t))) * 512 + h * 64 + d] = f2bf(oacc[cd][j]);
      }
  }
}

// ---------------- launch ----------------
extern "C" void kernel_launch(void* const* d_in, const int* in_sizes, int n_in,
                              void* d_out, int out_size, void* d_ws, size_t ws_size,
                              hipStream_t stream) {
  const float* q = (const float*)d_in[0];
  const float* kv = (const float*)d_in[1];
  const float* Wq = (const float*)d_in[2];
  const float* Wkv = (const float*)d_in[3];
  const float* Wfc = (const float*)d_in[4];
  float* out = (float*)d_out;
  char* ws = (char*)d_ws;

  // workspace layout (bytes)
  u16* q_bf  = (u16*)(ws + 0);            // 67108864  (also reused as o_buf)
  u16* kv_bf = (u16*)(ws + 67108864);     // 67108864
  u16* qp    = (u16*)(ws + 134217728);    // 67108864
  u16* kvp   = (u16*)(ws + 201326592);    // 134217728
  u16* Wq_t  = (u16*)(ws + 335544320);    // 524288
  u16* Wkv_t = (u16*)(ws + 336068608);    // 1048576
  u16* Wfc_t = (u16*)(ws + 337117184);    // 524288
  u16* o_buf = q_bf;                      // q_bf dead after GEMM1

  prep_kernel<<<4352, 256, 0, stream>>>(q, kv, Wq, Wkv, Wfc, q_bf, kv_bf, Wq_t, Wkv_t, Wfc_t);

  gemm256<false><<<(MM / 256) * (CC / 256), 512, 0, stream>>>(q_bf, Wq_t, qp, MM, CC, CC);
  gemm256<false><<<(MM / 256) * (2 * CC / 256), 512, 0, stream>>>(kv_bf, Wkv_t, kvp, MM, 2 * CC, CC);

  attn_kernel<<<BB * 64 * 8, 512, 0, stream>>>(qp, kvp, o_buf);

  gemm256<true><<<(MM / 256) * (CC / 256), 512, 0, stream>>>(o_buf, Wfc_t, out, MM, CC, CC);
}

// Round 10
// 356.254 us; speedup vs baseline: 1.0775x; 1.0260x over previous
//
#include <hip/hip_runtime.h>
#include <stdint.h>

#define BB 4
#define LL 16384
#define CC 512
#define MM (BB * LL)  // 65536

typedef unsigned short u16;
typedef __bf16 bf16x8 __attribute__((ext_vector_type(8)));
typedef float f32x4 __attribute__((ext_vector_type(4)));
typedef u16 u16x8 __attribute__((ext_vector_type(8)));
typedef u16 u16x4 __attribute__((ext_vector_type(4)));

__device__ __forceinline__ u16 f2bf(float f) {
  return __builtin_bit_cast(u16, (__bf16)f);
}

__device__ __forceinline__ void gl_lds16(const void* g, void* l) {
  __builtin_amdgcn_global_load_lds((const __attribute__((address_space(1))) void*)g,
                                   (__attribute__((address_space(3))) void*)l,
                                   16, 0, 0);
}

// ---------------- fused prep: fp32->bf16 cvt (q,kv) + weight transpose-cvt ----------
__global__ __launch_bounds__(256) void prep_kernel(
    const float* __restrict__ q, const float* __restrict__ kv,
    const float* __restrict__ Wq, const float* __restrict__ Wkv,
    const float* __restrict__ Wfc, u16* __restrict__ qo, u16* __restrict__ kvo,
    u16* __restrict__ Wq_t, u16* __restrict__ Wkv_t, u16* __restrict__ Wfc_t) {
  __shared__ float tile[64][65];
  const int bid = blockIdx.x, tid = threadIdx.x;

  if (bid < 4096) {
    const int half = bid >> 11;
    const float* src = half ? kv : q;
    u16* dst = half ? kvo : qo;
    const int n16 = MM * CC / 16;  // 2097152
    const int stride = 2048 * 256;
    for (int i = (bid & 2047) * 256 + tid; i < n16; i += stride) {
      f32x4 a0 = reinterpret_cast<const f32x4*>(src)[4 * i + 0];
      f32x4 a1 = reinterpret_cast<const f32x4*>(src)[4 * i + 1];
      f32x4 a2 = reinterpret_cast<const f32x4*>(src)[4 * i + 2];
      f32x4 a3 = reinterpret_cast<const f32x4*>(src)[4 * i + 3];
      u16x8 o0, o1;
      o0[0] = f2bf(a0[0]); o0[1] = f2bf(a0[1]); o0[2] = f2bf(a0[2]); o0[3] = f2bf(a0[3]);
      o0[4] = f2bf(a1[0]); o0[5] = f2bf(a1[1]); o0[6] = f2bf(a1[2]); o0[7] = f2bf(a1[3]);
      o1[0] = f2bf(a2[0]); o1[1] = f2bf(a2[1]); o1[2] = f2bf(a2[2]); o1[3] = f2bf(a2[3]);
      o1[4] = f2bf(a3[0]); o1[5] = f2bf(a3[1]); o1[6] = f2bf(a3[2]); o1[7] = f2bf(a3[3]);
      reinterpret_cast<u16x8*>(dst)[2 * i + 0] = o0;
      reinterpret_cast<u16x8*>(dst)[2 * i + 1] = o1;
    }
    return;
  }

  // weight transpose: W[K][N] -> Wt[N][K] bf16, 64x64 tiles
  const int wb = bid - 4096;
  const float* W; u16* Wt; int N, ti;
  if (wb < 64)       { W = Wq;  Wt = Wq_t;  N = 512;  ti = wb; }
  else if (wb < 192) { W = Wkv; Wt = Wkv_t; N = 1024; ti = wb - 64; }
  else               { W = Wfc; Wt = Wfc_t; N = 512;  ti = wb - 192; }
  const int ntn = N >> 6;
  const int kt = ti / ntn, nt = ti % ntn;
  const int k0 = kt << 6, n0 = nt << 6;
  {
    const int r = tid >> 4, c4 = tid & 15;
#pragma unroll
    for (int e = 0; e < 4; ++e) {
      int row = r + e * 16;
      f32x4 v = *reinterpret_cast<const f32x4*>(&W[(size_t)(k0 + row) * N + n0 + c4 * 4]);
      tile[row][c4 * 4 + 0] = v[0]; tile[row][c4 * 4 + 1] = v[1];
      tile[row][c4 * 4 + 2] = v[2]; tile[row][c4 * 4 + 3] = v[3];
    }
  }
  __syncthreads();
  {
    const int n = tid >> 2, qd = tid & 3;
#pragma unroll
    for (int e = 0; e < 2; ++e) {
      int c = qd * 2 + e;
      u16x8 o;
#pragma unroll
      for (int j = 0; j < 8; ++j) o[j] = f2bf(tile[c * 8 + j][n]);
      *reinterpret_cast<u16x8*>(&Wt[(size_t)(n0 + n) * 512 + k0 + c * 8]) = o;
    }
  }
}

// ---------------- 256x256 8-phase NT GEMM: C[M][N] = A[M][K] * Bt[N][K]^T ----------
// BM=BN=256, BK=64, 8 waves (2M x 4N). TRIPLE-buffered A + double-buffered B
// (160KB LDS, 1 block/CU): both operands staged 2 K-tiles ahead so the
// end-of-tile drain waits on loads issued a full tile (>=900cy) earlier.
// Tile u: reads A[cur]/B[cur]. Stages: p1 A(u+2)h0 -> A[sta] (idle since end of
// tile u-1); p2 A(u+2)h1 -> A[sta], B(u+2)h0 -> B[cur] (B[cur] reads all in p1,
// closed by p1-end barrier); p3 B(u+2)h1 -> B[cur]. End-of-tile vmcnt(8) drains
// A(u+1)+B(u+1) (issued during tile u-1), leaving tile-u's 8 stages in flight.
template <bool OUT_F32>
__global__ __launch_bounds__(512, 2) void gemm256(const u16* __restrict__ A,
                                                  const u16* __restrict__ Bt,
                                                  void* __restrict__ Cp,
                                                  int M, int N, int K) {
  __shared__ __align__(16) u16 Al[3][16384];
  __shared__ __align__(16) u16 Bl[2][16384];
  const int nbn = N >> 8;
  const int nwg = gridDim.x;
  const int bid0 = blockIdx.x;
  const int cpx = nwg >> 3;  // grid % 8 == 0 for all our shapes
  const int bid = (bid0 & 7) * cpx + (bid0 >> 3);
  const int bm = bid / nbn, bn = bid % nbn;
  const size_t row0 = (size_t)bm << 8, col0 = (size_t)bn << 8;
  const int tid = threadIdx.x, lane = tid & 63;
  const int wv = tid >> 6, wm = wv >> 2, wn = wv & 3;
  const int ro = lane & 15, g4 = lane >> 4;
  const int NT = K >> 6;

  // staging geometry: chunk ci covers (row=ci>>3, colgroup=ci&7) of a 128x64 half-tile.
  // LDS dest is LINEAR; global source colgroup pre-swizzled: gg = g ^ (row&7).
  const int ci0 = tid, ci1 = tid + 512;
  const int r0 = ci0 >> 3, g0 = (ci0 & 7) ^ (r0 & 7);
  const int r1 = ci1 >> 3, g1 = (ci1 & 7) ^ (r1 & 7);

  auto stageA = [&](int half, int kt, u16* L) {
    gl_lds16(A + (row0 + half * 128 + r0) * (size_t)K + kt * 64 + g0 * 8, L + half * 8192 + ci0 * 8);
    gl_lds16(A + (row0 + half * 128 + r1) * (size_t)K + kt * 64 + g1 * 8, L + half * 8192 + ci1 * 8);
  };
  auto stageB = [&](int half, int kt, u16* L) {
    gl_lds16(Bt + (col0 + half * 128 + r0) * (size_t)K + kt * 64 + g0 * 8, L + half * 8192 + ci0 * 8);
    gl_lds16(Bt + (col0 + half * 128 + r1) * (size_t)K + kt * 64 + g1 * 8, L + half * 8192 + ci1 * 8);
  };

  // ds_read offsets (u16 elements), swizzled: phys colgroup = logical ^ (row&7)
  const int aB = (wm * 128 + ro) * 64;
  const int bB = (wn * 64 + ro) * 64;
  const int sw0 = (g4 ^ (ro & 7)) * 8;
  const int sw1 = ((g4 + 4) ^ (ro & 7)) * 8;

  auto ldf = [&](const u16* p) { return *reinterpret_cast<const bf16x8*>(p); };

  f32x4 acc[8][4] = {};

  // prologue: issue A0,B0,A1,B1; drain A0+B0 (vmcnt(8) leaves A1,B1 in flight)
  stageA(0, 0, Al[0]); stageA(1, 0, Al[0]);
  stageB(0, 0, Bl[0]); stageB(1, 0, Bl[0]);
  stageA(0, 1, Al[1]); stageA(1, 1, Al[1]);
  stageB(0, 1, Bl[1]); stageB(1, 1, Bl[1]);
  asm volatile("s_waitcnt vmcnt(8)" ::: "memory");
  __builtin_amdgcn_s_barrier();

  u16* Acur = Al[0]; u16* Anxt = Al[1]; u16* Asta = Al[2];
  u16* Bcur = Bl[0]; u16* Bnxt = Bl[1];

  for (int u = 0; u < NT; ++u) {
    const bool st = (u + 2) < NT;
    bf16x8 bfr[4][2], af[2][2];

    // ---- phase 1: all B frags + A m0,m1; stage A(u+2) h0 into freed A buffer ----
#pragma unroll
    for (int n = 0; n < 4; ++n) {
      bfr[n][0] = ldf(Bcur + bB + n * 1024 + sw0);
      bfr[n][1] = ldf(Bcur + bB + n * 1024 + sw1);
    }
    af[0][0] = ldf(Acur + aB + sw0);        af[0][1] = ldf(Acur + aB + sw1);
    af[1][0] = ldf(Acur + aB + 1024 + sw0); af[1][1] = ldf(Acur + aB + 1024 + sw1);
    if (st) stageA(0, u + 2, Asta);
    __builtin_amdgcn_s_barrier();
    asm volatile("s_waitcnt lgkmcnt(0)" ::: "memory");
    __builtin_amdgcn_sched_barrier(0);
    __builtin_amdgcn_s_setprio(1);
#pragma unroll
    for (int m = 0; m < 2; ++m)
#pragma unroll
      for (int n = 0; n < 4; ++n) {
        acc[m][n] = __builtin_amdgcn_mfma_f32_16x16x32_bf16(af[m][0], bfr[n][0], acc[m][n], 0, 0, 0);
        acc[m][n] = __builtin_amdgcn_mfma_f32_16x16x32_bf16(af[m][1], bfr[n][1], acc[m][n], 0, 0, 0);
      }
    __builtin_amdgcn_s_setprio(0);
    __builtin_amdgcn_s_barrier();

    // ---- phases 2..4: A m=2ph..2ph+1; stage A(u+2)h1+B(u+2)h0 / B(u+2)h1 / - ----
#pragma unroll
    for (int ph = 1; ph < 4; ++ph) {
      af[0][0] = ldf(Acur + aB + (2 * ph) * 1024 + sw0);
      af[0][1] = ldf(Acur + aB + (2 * ph) * 1024 + sw1);
      af[1][0] = ldf(Acur + aB + (2 * ph + 1) * 1024 + sw0);
      af[1][1] = ldf(Acur + aB + (2 * ph + 1) * 1024 + sw1);
      if (ph == 1) { if (st) { stageA(1, u + 2, Asta); stageB(0, u + 2, Bcur); } }
      else if (ph == 2) { if (st) stageB(1, u + 2, Bcur); }
      __builtin_amdgcn_s_barrier();
      asm volatile("s_waitcnt lgkmcnt(0)" ::: "memory");
      __builtin_amdgcn_sched_barrier(0);
      __builtin_amdgcn_s_setprio(1);
#pragma unroll
      for (int m = 0; m < 2; ++m)
#pragma unroll
        for (int n = 0; n < 4; ++n) {
          acc[2 * ph + m][n] =
              __builtin_amdgcn_mfma_f32_16x16x32_bf16(af[m][0], bfr[n][0], acc[2 * ph + m][n], 0, 0, 0);
          acc[2 * ph + m][n] =
              __builtin_amdgcn_mfma_f32_16x16x32_bf16(af[m][1], bfr[n][1], acc[2 * ph + m][n], 0, 0, 0);
        }
      __builtin_amdgcn_s_setprio(0);
      if (ph == 3) {
        if (st) asm volatile("s_waitcnt vmcnt(8)" ::: "memory");
        else    asm volatile("s_waitcnt vmcnt(0)" ::: "memory");
      }
      __builtin_amdgcn_s_barrier();
    }

    // rotate buffers
    u16* ta = Acur; Acur = Anxt; Anxt = Asta; Asta = ta;
    u16* tb = Bcur; Bcur = Bnxt; Bnxt = tb;
  }

  // epilogue: C write
#pragma unroll
  for (int m = 0; m < 8; ++m)
#pragma unroll
    for (int n = 0; n < 4; ++n)
#pragma unroll
      for (int j = 0; j < 4; ++j) {
        size_t r = row0 + wm * 128 + m * 16 + g4 * 4 + j;
        size_t c = col0 + wn * 64 + n * 16 + ro;
        if (OUT_F32)
          reinterpret_cast<float*>(Cp)[r * N + c] = acc[m][n][j];
        else
          reinterpret_cast<u16*>(Cp)[r * N + c] = f2bf(acc[m][n][j]);
      }
}

// ---------------- window attention ----------------
// grid: b*512 + w*8 + h  (2048 blocks), 512 threads (8 waves, 32 q-rows each).
// K in LDS via global_load_lds with pre-swizzled source (32KB); V transposed in
// LDS, XOR-swizzled (32KB); P per-wave quarter-split, XOR-swizzled (16KB).
// Total exactly 80KB -> 2 blocks/CU.
__global__ __launch_bounds__(512, 4) void attn_kernel(const u16* __restrict__ qp,
                                                      const u16* __restrict__ kvp,
                                                      u16* __restrict__ o) {
  __shared__ __align__(16) u16 Kl[256 * 64];
  __shared__ __align__(16) u16 Vt[64 * 256];
  __shared__ __align__(16) u16 Pl[8 * 1024];
  const int bid = blockIdx.x;
  const int h = bid & 7, w = (bid >> 3) & 63, b = bid >> 9;
  const int w1 = w >> 3, w2 = w & 7;
  const int tid = threadIdx.x, lane = tid & 63, wv = tid >> 6;

  auto lrow = [&](int t) { return (w1 * 16 + (t >> 4)) * 128 + w2 * 16 + (t & 15); };

  // stage K: 2048 16B chunks; chunk ci = (row r = ci>>3, colgroup g = ci&7).
  // LDS dest linear; global source colgroup pre-swizzled g^(r&7).
#pragma unroll
  for (int p = 0; p < 4; ++p) {
    int ci = tid + p * 512;
    int r = ci >> 3, g = (ci & 7) ^ (r & 7);
    gl_lds16(kvp + ((size_t)(b * LL + lrow(r))) * 1024 + h * 64 + g * 8, Kl + ci * 8);
  }
  // stage V transposed, swizzled: logical (d, tk) at phys d*256 + ((tk>>3)^(d&7))*8 + (tk&7)
  {
    const int tk = tid >> 1, half = tid & 1;
    const size_t base = ((size_t)(b * LL + lrow(tk))) * 1024 + 512 + h * 64 + half * 32;
#pragma unroll
    for (int c = 0; c < 4; ++c) {
      u16x8 vx = *reinterpret_cast<const u16x8*>(kvp + base + c * 8);
#pragma unroll
      for (int e = 0; e < 8; ++e) {
        int d = half * 32 + c * 8 + e;
        Vt[d * 256 + (((tk >> 3) ^ (d & 7)) * 8) + (tk & 7)] = vx[e];
      }
    }
  }
  __syncthreads();

  const int ro = lane & 15;       // low nibble
  const int g4 = lane >> 4;       // lane group 0..3
  const float scale = 0.125f;     // hd^-0.5, hd=64
  const int swA = (g4 ^ (ro & 7)) * 8;
  const int swB = ((g4 + 4) ^ (ro & 7)) * 8;
  u16* PW = Pl + wv * 1024;

  auto ldf = [&](const u16* p) { return *reinterpret_cast<const bf16x8*>(p); };

#pragma unroll
  for (int rt = 0; rt < 2; ++rt) {
    // Q fragments for this 16-row tile, direct from global
    const int tq = 32 * wv + 16 * rt + ro;
    const size_t qbase = ((size_t)(b * LL + lrow(tq))) * 512 + h * 64 + g4 * 8;
    const bf16x8 qf0 = *reinterpret_cast<const bf16x8*>(qp + qbase);
    const bf16x8 qf1 = *reinterpret_cast<const bf16x8*>(qp + qbase + 32);

    // S = Q K^T : 16 q-rows x 256 keys; K frags from swizzled LDS
    f32x4 sa[16] = {};
    __builtin_amdgcn_s_setprio(1);
#pragma unroll
    for (int ct = 0; ct < 16; ++ct) {
      bf16x8 kf0 = ldf(Kl + (16 * ct + ro) * 64 + swA);
      bf16x8 kf1 = ldf(Kl + (16 * ct + ro) * 64 + swB);
      sa[ct] = __builtin_amdgcn_mfma_f32_16x16x32_bf16(qf0, kf0, sa[ct], 0, 0, 0);
      sa[ct] = __builtin_amdgcn_mfma_f32_16x16x32_bf16(qf1, kf1, sa[ct], 0, 0, 0);
    }
    __builtin_amdgcn_s_setprio(0);

    // softmax per q-row (row = g4*4 + j, key = 16*ct + ro)
#pragma unroll
    for (int j = 0; j < 4; ++j) {
      float m = -1e30f;
#pragma unroll
      for (int ct = 0; ct < 16; ++ct) m = fmaxf(m, sa[ct][j]);
      m = fmaxf(m, __shfl_xor(m, 1));
      m = fmaxf(m, __shfl_xor(m, 2));
      m = fmaxf(m, __shfl_xor(m, 4));
      m = fmaxf(m, __shfl_xor(m, 8));
      m *= scale;
      float s = 0.f;
#pragma unroll
      for (int ct = 0; ct < 16; ++ct) {
        float p = __expf(sa[ct][j] * scale - m);
        sa[ct][j] = p;
        s += p;
      }
      s += __shfl_xor(s, 1);
      s += __shfl_xor(s, 2);
      s += __shfl_xor(s, 4);
      s += __shfl_xor(s, 8);
      float inv = 1.f / s;
#pragma unroll
      for (int ct = 0; ct < 16; ++ct) sa[ct][j] *= inv;
    }

    // O = P V in four key-quarters through the per-wave swizzled LDS P tile.
    // In-wave DS ordering makes write->read->overwrite safe without barriers.
    f32x4 oacc[4] = {};
#pragma unroll
    for (int kh = 0; kh < 4; ++kh) {
#pragma unroll
      for (int c = 0; c < 4; ++c)
#pragma unroll
        for (int j = 0; j < 4; ++j) {
          int rq = g4 * 4 + j;
          PW[rq * 64 + (((2 * c + (ro >> 3)) ^ (rq & 7)) * 8) + (ro & 7)] =
              f2bf(sa[kh * 4 + c][j]);
        }
      __builtin_amdgcn_s_setprio(1);
#pragma unroll
      for (int ks = 0; ks < 2; ++ks) {
        bf16x8 pf = ldf(PW + ro * 64 + (((ks * 4 + g4) ^ (ro & 7)) * 8));
        const int kkg = kh * 2 + ks;
#pragma unroll
        for (int cd = 0; cd < 4; ++cd) {
          bf16x8 vf = ldf(Vt + (16 * cd + ro) * 256 + (((kkg * 4 + g4) ^ (ro & 7)) * 8));
          oacc[cd] = __builtin_amdgcn_mfma_f32_16x16x32_bf16(pf, vf, oacc[cd], 0, 0, 0);
        }
      }
      __builtin_amdgcn_s_setprio(0);
    }

    // write out this 16-row tile
#pragma unroll
    for (int cd = 0; cd < 4; ++cd)
#pragma unroll
      for (int j = 0; j < 4; ++j) {
        int t = 32 * wv + 16 * rt + g4 * 4 + j;
        int d = 16 * cd + ro;
        o[((size_t)(b * LL + lrow(t))) * 512 + h * 64 + d] = f2bf(oacc[cd][j]);
      }
  }
}

// ---------------- launch ----------------
extern "C" void kernel_launch(void* const* d_in, const int* in_sizes, int n_in,
                              void* d_out, int out_size, void* d_ws, size_t ws_size,
                              hipStream_t stream) {
  const float* q = (const float*)d_in[0];
  const float* kv = (const float*)d_in[1];
  const float* Wq = (const float*)d_in[2];
  const float* Wkv = (const float*)d_in[3];
  const float* Wfc = (const float*)d_in[4];
  float* out = (float*)d_out;
  char* ws = (char*)d_ws;

  // workspace layout (bytes)
  u16* q_bf  = (u16*)(ws + 0);            // 67108864  (also reused as o_buf)
  u16* kv_bf = (u16*)(ws + 67108864);     // 67108864
  u16* qp    = (u16*)(ws + 134217728);    // 67108864
  u16* kvp   = (u16*)(ws + 201326592);    // 134217728
  u16* Wq_t  = (u16*)(ws + 335544320);    // 524288
  u16* Wkv_t = (u16*)(ws + 336068608);    // 1048576
  u16* Wfc_t = (u16*)(ws + 337117184);    // 524288
  u16* o_buf = q_bf;                      // q_bf dead after GEMM1

  prep_kernel<<<4352, 256, 0, stream>>>(q, kv, Wq, Wkv, Wfc, q_bf, kv_bf, Wq_t, Wkv_t, Wfc_t);

  gemm256<false><<<(MM / 256) * (CC / 256), 512, 0, stream>>>(q_bf, Wq_t, qp, MM, CC, CC);
  gemm256<false><<<(MM / 256) * (2 * CC / 256), 512, 0, stream>>>(kv_bf, Wkv_t, kvp, MM, 2 * CC, CC);

  attn_kernel<<<BB * 64 * 8, 512, 0, stream>>>(qp, kvp, o_buf);

  gemm256<true><<<(MM / 256) * (CC / 256), 512, 0, stream>>>(o_buf, Wfc_t, out, MM, CC, CC);
}